// Round 5
// baseline (669.615 us; speedup 1.0000x reference)
//
#include <hip/hip_runtime.h>
#include <hip/hip_bf16.h>

typedef __hip_bfloat16 bf16;
typedef __attribute__((ext_vector_type(8))) __bf16 bf16x8;
typedef __attribute__((ext_vector_type(4))) float f32x4;

#define B_ 16384
#define D_ 1024
#define H_ 512
#define O_ 256
#define E_ 8
#define BC_ 8192   // B-chunk rows for expert L1/L2/L3 (ws budget)

// async global->LDS, 16B per lane (m97: the 874 TF staging path).
#define GLDS(src, dst) __builtin_amdgcn_global_load_lds( \
    (const __attribute__((address_space(1))) void*)(src), \
    (__attribute__((address_space(3))) void*)(dst), 16, 0, 0)

// ---------------------------------------------------------------------------
// Input-dtype detector. flag=1 => inputs are fp32 (bf16 N(0,1) never has
// exponent>=150; fp32 mantissa halves hit it with p~0.41/sample).
// ---------------------------------------------------------------------------
__global__ void detect_k(const unsigned short* __restrict__ x, int* __restrict__ flag) {
    __shared__ int s;
    if (threadIdx.x == 0) s = 0;
    __syncthreads();
    int big = 0;
    for (int i = threadIdx.x; i < 2048; i += 256)
        if (((x[i] >> 7) & 0xFF) >= 150) big = 1;
    if (big) atomicOr(&s, 1);
    __syncthreads();
    if (threadIdx.x == 0) *flag = s;
}

// canonicalize any input to bf16 (grid-stride)
__global__ void cvt_k(const void* __restrict__ src, bf16* __restrict__ dst,
                      const int* __restrict__ flag, long n) {
    const int f = *flag;
    long i = (long)blockIdx.x * blockDim.x + threadIdx.x;
    const long stride = (long)gridDim.x * blockDim.x;
    if (f) {
        const float* s = (const float*)src;
        for (; i < n; i += stride) dst[i] = __float2bfloat16(s[i]);
    } else {
        const bf16* s = (const bf16*)src;
        for (; i < n; i += stride) dst[i] = s[i];
    }
}

// ---------------------------------------------------------------------------
// Batched 2D transpose + canonicalize: in [Z][R][C] -> out bf16 [Z][C][R]
// ---------------------------------------------------------------------------
__global__ void transpose_k(const void* __restrict__ in, bf16* __restrict__ out,
                            const int* __restrict__ flag, int R, int C) {
    __shared__ bf16 t[32][33];
    const int f = *flag;
    const long zo = (long)blockIdx.z * R * C;
    const int x = blockIdx.x * 32 + threadIdx.x;
    const int y0 = blockIdx.y * 32;
    const float* inf = (const float*)in;
    const bf16* inb = (const bf16*)in;
#pragma unroll
    for (int i = 0; i < 4; i++) {
        int r = y0 + threadIdx.y + i * 8;
        long idx = zo + (long)r * C + x;
        t[threadIdx.y + i * 8][threadIdx.x] =
            f ? __float2bfloat16(inf[idx]) : inb[idx];
    }
    __syncthreads();
    const int xr = blockIdx.y * 32 + threadIdx.x;
#pragma unroll
    for (int i = 0; i < 4; i++) {
        int c = blockIdx.x * 32 + threadIdx.y + i * 8;
        out[zo + (long)c * R + xr] = t[threadIdx.x][threadIdx.y + i * 8];
    }
}

// ---------------------------------------------------------------------------
// Gating layer 3 + softmax: g2 [B,128] @ gw3 [128,8] + gb3 -> softmax -> gates
// ---------------------------------------------------------------------------
__global__ void gate3_softmax_k(const bf16* __restrict__ g2,
                                const bf16* __restrict__ gw3,
                                const bf16* __restrict__ gb3,
                                float* __restrict__ gates) {
    __shared__ float w[128 * 8];
    __shared__ float bsh[8];
    const int tid = threadIdx.x;
    for (int i = tid; i < 1024; i += 256) w[i] = __bfloat162float(gw3[i]);
    if (tid < 8) bsh[tid] = __bfloat162float(gb3[tid]);
    __syncthreads();

    const long row = (long)blockIdx.x * 256 + tid;
    float acc[8];
#pragma unroll
    for (int o = 0; o < 8; o++) acc[o] = bsh[o];

    const bf16x8* rp8 = (const bf16x8*)(g2 + row * 128);
#pragma unroll 4
    for (int c8 = 0; c8 < 16; c8++) {
        bf16x8 v8 = rp8[c8];
#pragma unroll
        for (int jj = 0; jj < 8; jj++) {
            float v = (float)v8[jj];
            int k = c8 * 8 + jj;
#pragma unroll
            for (int o = 0; o < 8; o++) acc[o] += v * w[k * 8 + o];
        }
    }
    float m = acc[0];
#pragma unroll
    for (int o = 1; o < 8; o++) m = fmaxf(m, acc[o]);
    float s = 0.f;
#pragma unroll
    for (int o = 0; o < 8; o++) { acc[o] = __expf(acc[o] - m); s += acc[o]; }
    const float inv = 1.f / s;
#pragma unroll
    for (int o = 0; o < 8; o++) gates[row * 8 + o] = acc[o] * inv;
}

// ---------------------------------------------------------------------------
// Core GEMM: C[M,N] = A[M,K] * Bt[N,K]^T, 128x128 tile, BK=32, 4 waves,
// global_load_lds width=16 staging (m97). Fragment maps per m89/m91.
// row0: global-row offset of A's row 0 (for gates / output indexing).
// MODE 0: out = bf16(relu(acc + bias[c]))
// MODE 1: out = bf16(relu(acc + bias[c]) * gates[row0+r, e])
// MODE 2: outf32[r,c] += acc + gates[row0+r,e]*eb3[e,c]       (single-block K)
// MODE 4: atomicAdd(outf32[row0+r,c],
//                   acc + sum_{s<epz} gates[row0+r, z*epz+s]*eb3[z*epz+s, c])
//         split-K over z: each z covers epz experts (e_gate=epz, k_per_e set).
// ---------------------------------------------------------------------------
template <int MODE>
__global__ __launch_bounds__(256, 2)
void gemm_bt(const bf16* __restrict__ A, const bf16* __restrict__ Bt,
             const bf16* __restrict__ bias, const float* __restrict__ gates,
             void* __restrict__ Cout, const bf16* __restrict__ eb3,
             const int* __restrict__ oflag,
             int lda, int ldb, int ldo, int K,
             long a_z, long b_z, long bias_z, long out_z,
             int e_gate, int k_per_e, long a_e, long b_e, long row0) {
    __shared__ __attribute__((aligned(16))) bf16 As[128 * 32];
    __shared__ __attribute__((aligned(16))) bf16 Bs[128 * 32];

    const int tid  = threadIdx.x;
    const int lane = tid & 63;
    const int quad = lane >> 4;
    const int l15  = lane & 15;
    const int wid  = tid >> 6;
    const int wr   = (wid >> 1) << 6;
    const int wc   = (wid & 1) << 6;
    const int z    = blockIdx.z;
    const long m0  = (long)blockIdx.y << 7;
    const long n0  = (long)blockIdx.x << 7;

    const bf16* Az = A + (long)z * a_z;
    const bf16* Bz = Bt + (long)z * b_z;

    f32x4 acc[4][4];
#pragma unroll
    for (int i = 0; i < 4; i++)
#pragma unroll
        for (int j = 0; j < 4; j++) acc[i][j] = (f32x4){0.f, 0.f, 0.f, 0.f};

    const int erow = tid >> 2;          // 0..63
    const int ecol = (tid & 3) << 3;    // 0,8,16,24

    const int n_e   = k_per_e ? (K / k_per_e) : 1;
    const int inner = (k_per_e ? k_per_e : K) >> 5;

    for (int e = 0; e < n_e; e++) {
        const bf16* Ae = Az + (long)e * a_e;
        const bf16* Be = Bz + (long)e * b_e;
        for (int kti = 0; kti < inner; kti++) {
            const int kk = kti << 5;
#pragma unroll
            for (int i = 0; i < 2; i++) {
                const int r = (i << 6) + erow;
                GLDS(Ae + (m0 + r) * lda + (kk + ecol), As + r * 32 + ecol);
            }
#pragma unroll
            for (int i = 0; i < 2; i++) {
                const int r = (i << 6) + erow;
                GLDS(Be + (n0 + r) * ldb + (kk + ecol), Bs + r * 32 + ecol);
            }
            __syncthreads();   // drains vmcnt: GLDS data visible
            bf16x8 af[4], bfr[4];
#pragma unroll
            for (int i = 0; i < 4; i++)
                af[i] = *(const bf16x8*)(As + (wr + i * 16 + l15) * 32 + (quad << 3));
#pragma unroll
            for (int j = 0; j < 4; j++)
                bfr[j] = *(const bf16x8*)(Bs + (wc + j * 16 + l15) * 32 + (quad << 3));
#pragma unroll
            for (int i = 0; i < 4; i++)
#pragma unroll
                for (int j = 0; j < 4; j++)
                    acc[i][j] = __builtin_amdgcn_mfma_f32_16x16x32_bf16(
                        af[i], bfr[j], acc[i][j], 0, 0, 0);
            __syncthreads();   // protect LDS from next tile's stores
        }
    }

    // ------------------ epilogue (C/D: row=quad*4+reg, col=lane&15) --------
    const int eg = (e_gate >= 0) ? e_gate : z;

    if constexpr (MODE == 0 || MODE == 1) {
        bf16* C = (bf16*)Cout + (long)z * out_z;
        const bf16* bb = bias + (long)z * bias_z;
        float gv[4][4];
        if constexpr (MODE == 1) {
#pragma unroll
            for (int i = 0; i < 4; i++)
#pragma unroll
                for (int rg = 0; rg < 4; rg++)
                    gv[i][rg] = gates[(row0 + m0 + wr + i * 16 + quad * 4 + rg) * 8 + eg];
        }
#pragma unroll
        for (int j = 0; j < 4; j++) {
            const int c = (int)n0 + wc + j * 16 + l15;
            const float bv = __bfloat162float(bb[c]);
#pragma unroll
            for (int i = 0; i < 4; i++) {
#pragma unroll
                for (int rg = 0; rg < 4; rg++) {
                    const long r = m0 + wr + i * 16 + quad * 4 + rg;
                    float v = fmaxf(acc[i][j][rg] + bv, 0.f);
                    if constexpr (MODE == 1) v *= gv[i][rg];
                    C[r * ldo + c] = __float2bfloat16(v);
                }
            }
        }
    } else if constexpr (MODE == 2) {
        float* C = (float*)Cout;
#pragma unroll
        for (int i = 0; i < 4; i++) {
#pragma unroll
            for (int rg = 0; rg < 4; rg++) {
                const long r = m0 + wr + i * 16 + quad * 4 + rg;
                const float g = gates[(row0 + r) * 8 + eg];
#pragma unroll
                for (int j = 0; j < 4; j++) {
                    const int c = (int)n0 + wc + j * 16 + l15;
                    const float b3 = __bfloat162float(eb3[eg * O_ + c]);
                    C[r * ldo + c] += acc[i][j][rg] + g * b3;
                }
            }
        }
    } else {  // MODE == 4: split-K atomic accumulate into fp32 out
        float* C = (float*)Cout;
        const int epz = e_gate;          // experts per z-split
        const int e0  = z * epz;
        float b3[4][8];
#pragma unroll
        for (int j = 0; j < 4; j++) {
            const int c = (int)n0 + wc + j * 16 + l15;
            for (int s = 0; s < epz; s++)
                b3[j][s] = __bfloat162float(eb3[(e0 + s) * O_ + c]);
        }
#pragma unroll
        for (int i = 0; i < 4; i++) {
#pragma unroll
            for (int rg = 0; rg < 4; rg++) {
                const long r = m0 + wr + i * 16 + quad * 4 + rg;
                const float* gp = gates + (row0 + r) * 8 + e0;
#pragma unroll
                for (int j = 0; j < 4; j++) {
                    const int c = (int)n0 + wc + j * 16 + l15;
                    float v = acc[i][j][rg];
                    for (int s = 0; s < epz; s++) v += gp[s] * b3[j][s];
                    atomicAdd(C + (row0 + r) * ldo + c, v);
                }
            }
        }
    }
}

// ---------------------------------------------------------------------------
__global__ void zero_f32_k(float* __restrict__ p) {
    p[(long)blockIdx.x * 256 + threadIdx.x] = 0.f;
}
__global__ void out_cvt_k(const float* __restrict__ in, void* __restrict__ out,
                          const int* __restrict__ flag) {
    const long i = (long)blockIdx.x * 256 + threadIdx.x;
    if (*flag) ((float*)out)[i] = in[i];
    else       ((bf16*)out)[i] = __float2bfloat16(in[i]);
}

// ---------------------------------------------------------------------------
extern "C" void kernel_launch(void* const* d_in, const int* in_sizes, int n_in,
                              void* d_out, int out_size, void* d_ws, size_t ws_size,
                              hipStream_t stream) {
    (void)in_sizes; (void)n_in; (void)out_size;
    const void* x   = d_in[0];
    const void* gw1 = d_in[1];
    const void* gb1 = d_in[2];
    const void* gw2 = d_in[3];
    const void* gb2 = d_in[4];
    const void* gw3 = d_in[5];
    const void* gb3 = d_in[6];
    const void* ew1 = d_in[7];
    const void* eb1 = d_in[8];
    const void* ew2 = d_in[9];
    const void* eb2 = d_in[10];
    const void* ew3 = d_in[11];
    const void* eb3 = d_in[12];

    char* ws = (char*)d_ws;
    size_t off = 0;
    auto alloc = [&](size_t n) { char* p = ws + off; off += (n + 255) & ~(size_t)255; return p; };

    int*  flag  = (int*)alloc(256);
    bf16* xc    = (bf16*)alloc((size_t)B_ * D_ * 2);
    bf16* gw1t  = (bf16*)alloc((size_t)256 * 1024 * 2);
    bf16* gw2t  = (bf16*)alloc((size_t)128 * 256 * 2);
    bf16* ew1t  = (bf16*)alloc((size_t)E_ * H_ * D_ * 2);
    bf16* ew2t  = (bf16*)alloc((size_t)E_ * H_ * H_ * 2);
    bf16* ew3t  = (bf16*)alloc((size_t)E_ * O_ * H_ * 2);
    bf16* gb1c  = (bf16*)alloc(256 * 2);
    bf16* gb2c  = (bf16*)alloc(128 * 2);
    bf16* gw3c  = (bf16*)alloc(1024 * 2);
    bf16* gb3c  = (bf16*)alloc(8 * 2);
    bf16* eb1c  = (bf16*)alloc((size_t)E_ * H_ * 2);
    bf16* eb2c  = (bf16*)alloc((size_t)E_ * H_ * 2);
    bf16* eb3c  = (bf16*)alloc((size_t)E_ * O_ * 2);
    bf16* g1    = (bf16*)alloc((size_t)B_ * 256 * 2);
    bf16* g2b   = (bf16*)alloc((size_t)B_ * 128 * 2);
    float* gates = (float*)alloc((size_t)B_ * 8 * 4);

    const size_t small = off;
    // chunked path: h1c + h2c ([E][BC][H] each) + oacc fp32 [B][O]
    const size_t needA = small + 2ull * ((size_t)E_ * BC_ * H_ * 2 + 256)
                               + ((size_t)B_ * O_ * 4 + 256) + 4096;
    const bool pathA = ws_size >= needA;

    // 1) detect input dtype (flag=1 -> fp32)
    detect_k<<<1, 256, 0, stream>>>((const unsigned short*)x, flag);

    // 2) canonicalize to bf16
    cvt_k<<<4096, 256, 0, stream>>>(x, xc, flag, (long)B_ * D_);
    cvt_k<<<1, 256, 0, stream>>>(gb1, gb1c, flag, 256);
    cvt_k<<<1, 256, 0, stream>>>(gb2, gb2c, flag, 128);
    cvt_k<<<4, 256, 0, stream>>>(gw3, gw3c, flag, 1024);
    cvt_k<<<1, 256, 0, stream>>>(gb3, gb3c, flag, 8);
    cvt_k<<<16, 256, 0, stream>>>(eb1, eb1c, flag, (long)E_ * H_);
    cvt_k<<<16, 256, 0, stream>>>(eb2, eb2c, flag, (long)E_ * H_);
    cvt_k<<<8, 256, 0, stream>>>(eb3, eb3c, flag, (long)E_ * O_);

    // 3) weight transposes (K-contiguous rows, canonical bf16)
    transpose_k<<<dim3(256 / 32, 1024 / 32, 1), dim3(32, 8), 0, stream>>>(gw1, gw1t, flag, 1024, 256);
    transpose_k<<<dim3(128 / 32, 256 / 32, 1), dim3(32, 8), 0, stream>>>(gw2, gw2t, flag, 256, 128);
    transpose_k<<<dim3(H_ / 32, D_ / 32, E_), dim3(32, 8), 0, stream>>>(ew1, ew1t, flag, D_, H_);
    transpose_k<<<dim3(H_ / 32, H_ / 32, E_), dim3(32, 8), 0, stream>>>(ew2, ew2t, flag, H_, H_);
    transpose_k<<<dim3(O_ / 32, H_ / 32, E_), dim3(32, 8), 0, stream>>>(ew3, ew3t, flag, H_, O_);

    // 4) gating network
    gemm_bt<0><<<dim3(2, 128, 1), 256, 0, stream>>>(
        xc, gw1t, gb1c, nullptr, g1, nullptr, nullptr,
        1024, 1024, 256, 1024, 0, 0, 0, 0, 0, 0, 0, 0, 0);
    gemm_bt<0><<<dim3(1, 128, 1), 256, 0, stream>>>(
        g1, gw2t, gb2c, nullptr, g2b, nullptr, nullptr,
        256, 256, 128, 256, 0, 0, 0, 0, 0, 0, 0, 0, 0);
    gate3_softmax_k<<<dim3(B_ / 256), 256, 0, stream>>>(g2b, gw3c, gb3c, gates);

    // 5) experts
    if (pathA) {
        bf16* h1c = (bf16*)alloc((size_t)E_ * BC_ * H_ * 2);
        bf16* h2c = (bf16*)alloc((size_t)E_ * BC_ * H_ * 2);
        float* oacc = (float*)alloc((size_t)B_ * O_ * 4);
        zero_f32_k<<<dim3(B_ * O_ / 256), 256, 0, stream>>>(oacc);
        for (int ci = 0; ci < B_ / BC_; ci++) {
            const long rb = (long)ci * BC_;
            // L1 (batched z=e): h1c[e][0..BC)[H] = relu(x_chunk @ ew1[e] + eb1[e])
            gemm_bt<0><<<dim3(4, BC_ / 128, 8), 256, 0, stream>>>(
                xc + rb * D_, ew1t, eb1c, nullptr, h1c, nullptr, nullptr,
                D_, D_, H_, D_,
                0, (long)H_ * D_, H_, (long)BC_ * H_, 0, 0, 0, 0, 0);
            // L2 (batched, gate folded): h2c[e][0..BC)[H]
            gemm_bt<1><<<dim3(4, BC_ / 128, 8), 256, 0, stream>>>(
                h1c, ew2t, eb2c, gates, h2c, nullptr, nullptr,
                H_, H_, H_, H_,
                (long)BC_ * H_, (long)H_ * H_, H_, (long)BC_ * H_, -1, 0, 0, 0, rb);
            // L3 split-K atomic: z=4 splits x 2 experts (K=1024 each)
            gemm_bt<4><<<dim3(2, BC_ / 128, 4), 256, 0, stream>>>(
                h2c, ew3t, nullptr, gates, oacc, eb3c, nullptr,
                H_, H_, O_, 1024,
                2L * BC_ * H_, 2L * O_ * H_, 0, 0,
                2 /*epz*/, 512, (long)BC_ * H_, (long)O_ * H_, rb);
        }
        out_cvt_k<<<dim3(B_ * O_ / 256), 256, 0, stream>>>(oacc, d_out, flag);
    } else {
        bf16* h1s = (bf16*)alloc((size_t)B_ * H_ * 2);
        bf16* h2s = (bf16*)alloc((size_t)B_ * H_ * 2);
        float* oacc = (float*)alloc((size_t)B_ * O_ * 4);
        zero_f32_k<<<dim3(B_ * O_ / 256), 256, 0, stream>>>(oacc);
        for (int e = 0; e < E_; e++) {
            gemm_bt<0><<<dim3(4, 128, 1), 256, 0, stream>>>(
                xc, ew1t + (size_t)e * H_ * D_, eb1c + (size_t)e * H_, nullptr, h1s, nullptr, nullptr,
                1024, 1024, 512, 1024, 0, 0, 0, 0, 0, 0, 0, 0, 0);
            gemm_bt<1><<<dim3(4, 128, 1), 256, 0, stream>>>(
                h1s, ew2t + (size_t)e * H_ * H_, eb2c + (size_t)e * H_, gates, h2s, nullptr, nullptr,
                512, 512, 512, 512, 0, 0, 0, 0, e, 0, 0, 0, 0);
            gemm_bt<2><<<dim3(2, 128, 1), 256, 0, stream>>>(
                h2s, ew3t + (size_t)e * O_ * H_, nullptr, gates, oacc, eb3c, nullptr,
                512, 512, 256, 512, 0, 0, 0, 0, e, 0, 0, 0, 0);
        }
        out_cvt_k<<<dim3(B_ * O_ / 256), 256, 0, stream>>>(oacc, d_out, flag);
    }
}

// Round 6
// 591.226 us; speedup vs baseline: 1.1326x; 1.1326x over previous
//
#include <hip/hip_runtime.h>
#include <hip/hip_bf16.h>

typedef __hip_bfloat16 bf16;
typedef __attribute__((ext_vector_type(8))) __bf16 bf16x8;
typedef __attribute__((ext_vector_type(4))) float f32x4;

#define B_ 16384
#define D_ 1024
#define H_ 512
#define O_ 256
#define E_ 8
#define BC_ 8192   // B-chunk rows for expert L1/L2/L3 (ws budget)

// async global->LDS, 16B per lane (m97: the 874 TF staging path).
#define GLDS(src, dst) __builtin_amdgcn_global_load_lds( \
    (const __attribute__((address_space(1))) void*)(src), \
    (__attribute__((address_space(3))) void*)(dst), 16, 0, 0)

// ---------------------------------------------------------------------------
// Input-dtype detector. flag=1 => inputs are fp32.
// ---------------------------------------------------------------------------
__global__ void detect_k(const unsigned short* __restrict__ x, int* __restrict__ flag) {
    __shared__ int s;
    if (threadIdx.x == 0) s = 0;
    __syncthreads();
    int big = 0;
    for (int i = threadIdx.x; i < 2048; i += 256)
        if (((x[i] >> 7) & 0xFF) >= 150) big = 1;
    if (big) atomicOr(&s, 1);
    __syncthreads();
    if (threadIdx.x == 0) *flag = s;
}

// canonicalize any input to bf16 (grid-stride)
__global__ void cvt_k(const void* __restrict__ src, bf16* __restrict__ dst,
                      const int* __restrict__ flag, long n) {
    const int f = *flag;
    long i = (long)blockIdx.x * blockDim.x + threadIdx.x;
    const long stride = (long)gridDim.x * blockDim.x;
    if (f) {
        const float* s = (const float*)src;
        for (; i < n; i += stride) dst[i] = __float2bfloat16(s[i]);
    } else {
        const bf16* s = (const bf16*)src;
        for (; i < n; i += stride) dst[i] = s[i];
    }
}

// ---------------------------------------------------------------------------
// Batched 2D transpose + canonicalize: in [Z][R][C] -> out bf16 [Z][C][R]
// ---------------------------------------------------------------------------
__global__ void transpose_k(const void* __restrict__ in, bf16* __restrict__ out,
                            const int* __restrict__ flag, int R, int C) {
    __shared__ bf16 t[32][33];
    const int f = *flag;
    const long zo = (long)blockIdx.z * R * C;
    const int x = blockIdx.x * 32 + threadIdx.x;
    const int y0 = blockIdx.y * 32;
    const float* inf = (const float*)in;
    const bf16* inb = (const bf16*)in;
#pragma unroll
    for (int i = 0; i < 4; i++) {
        int r = y0 + threadIdx.y + i * 8;
        long idx = zo + (long)r * C + x;
        t[threadIdx.y + i * 8][threadIdx.x] =
            f ? __float2bfloat16(inf[idx]) : inb[idx];
    }
    __syncthreads();
    const int xr = blockIdx.y * 32 + threadIdx.x;
#pragma unroll
    for (int i = 0; i < 4; i++) {
        int c = blockIdx.x * 32 + threadIdx.y + i * 8;
        out[zo + (long)c * R + xr] = t[threadIdx.x][threadIdx.y + i * 8];
    }
}

// ---------------------------------------------------------------------------
// Gating layer 3 + softmax: g2 [B,128] @ gw3 [128,8] + gb3 -> softmax -> gates
// ---------------------------------------------------------------------------
__global__ void gate3_softmax_k(const bf16* __restrict__ g2,
                                const bf16* __restrict__ gw3,
                                const bf16* __restrict__ gb3,
                                float* __restrict__ gates) {
    __shared__ float w[128 * 8];
    __shared__ float bsh[8];
    const int tid = threadIdx.x;
    for (int i = tid; i < 1024; i += 256) w[i] = __bfloat162float(gw3[i]);
    if (tid < 8) bsh[tid] = __bfloat162float(gb3[tid]);
    __syncthreads();

    const long row = (long)blockIdx.x * 256 + tid;
    float acc[8];
#pragma unroll
    for (int o = 0; o < 8; o++) acc[o] = bsh[o];

    const bf16x8* rp8 = (const bf16x8*)(g2 + row * 128);
#pragma unroll 4
    for (int c8 = 0; c8 < 16; c8++) {
        bf16x8 v8 = rp8[c8];
#pragma unroll
        for (int jj = 0; jj < 8; jj++) {
            float v = (float)v8[jj];
            int k = c8 * 8 + jj;
#pragma unroll
            for (int o = 0; o < 8; o++) acc[o] += v * w[k * 8 + o];
        }
    }
    float m = acc[0];
#pragma unroll
    for (int o = 1; o < 8; o++) m = fmaxf(m, acc[o]);
    float s = 0.f;
#pragma unroll
    for (int o = 0; o < 8; o++) { acc[o] = __expf(acc[o] - m); s += acc[o]; }
    const float inv = 1.f / s;
#pragma unroll
    for (int o = 0; o < 8; o++) gates[row * 8 + o] = acc[o] * inv;
}

// ---------------------------------------------------------------------------
// Core GEMM: C[M,N] = A[M,K] * Bt[N,K]^T, 128x128 tile, BK=32, 4 waves,
// global_load_lds width=16 staging (m97). Fragment maps per m89/m91.
// row0: global-row offset of A's row 0 (for gates / output indexing).
// MODE 0: out = bf16(relu(acc + bias[c]))
// MODE 1: out = bf16(relu(acc + bias[c]) * gates[row0+r, e])
// MODE 2: outf32[r,c] += acc + gates[row0+r,e]*eb3[e,c]       (path B)
// MODE 5: parts[z][row0+r][c] = acc + sum_{s<2} gates[row0+r, 2z+s]*eb3[2z+s,c]
//         split-K over z (2 experts per split), plain stores, no atomics.
// ---------------------------------------------------------------------------
template <int MODE>
__global__ __launch_bounds__(256, 4)
void gemm_bt(const bf16* __restrict__ A, const bf16* __restrict__ Bt,
             const bf16* __restrict__ bias, const float* __restrict__ gates,
             void* __restrict__ Cout, const bf16* __restrict__ eb3,
             const int* __restrict__ oflag,
             int lda, int ldb, int ldo, int K,
             long a_z, long b_z, long bias_z, long out_z,
             int e_gate, int k_per_e, long a_e, long b_e, long row0) {
    __shared__ __attribute__((aligned(16))) bf16 As[128 * 32];
    __shared__ __attribute__((aligned(16))) bf16 Bs[128 * 32];

    const int tid  = threadIdx.x;
    const int lane = tid & 63;
    const int quad = lane >> 4;
    const int l15  = lane & 15;
    const int wid  = tid >> 6;
    const int wr   = (wid >> 1) << 6;
    const int wc   = (wid & 1) << 6;
    const int z    = blockIdx.z;
    const long m0  = (long)blockIdx.y << 7;
    const long n0  = (long)blockIdx.x << 7;

    const bf16* Az = A + (long)z * a_z;
    const bf16* Bz = Bt + (long)z * b_z;

    f32x4 acc[4][4];
#pragma unroll
    for (int i = 0; i < 4; i++)
#pragma unroll
        for (int j = 0; j < 4; j++) acc[i][j] = (f32x4){0.f, 0.f, 0.f, 0.f};

    const int erow = tid >> 2;          // 0..63
    const int ecol = (tid & 3) << 3;    // 0,8,16,24

    const int n_e   = k_per_e ? (K / k_per_e) : 1;
    const int inner = (k_per_e ? k_per_e : K) >> 5;

    for (int e = 0; e < n_e; e++) {
        const bf16* Ae = Az + (long)e * a_e;
        const bf16* Be = Bz + (long)e * b_e;
        for (int kti = 0; kti < inner; kti++) {
            const int kk = kti << 5;
#pragma unroll
            for (int i = 0; i < 2; i++) {
                const int r = (i << 6) + erow;
                GLDS(Ae + (m0 + r) * lda + (kk + ecol), As + r * 32 + ecol);
            }
#pragma unroll
            for (int i = 0; i < 2; i++) {
                const int r = (i << 6) + erow;
                GLDS(Be + (n0 + r) * ldb + (kk + ecol), Bs + r * 32 + ecol);
            }
            __syncthreads();   // drains vmcnt: GLDS data visible
            bf16x8 af[4], bfr[4];
#pragma unroll
            for (int i = 0; i < 4; i++)
                af[i] = *(const bf16x8*)(As + (wr + i * 16 + l15) * 32 + (quad << 3));
#pragma unroll
            for (int j = 0; j < 4; j++)
                bfr[j] = *(const bf16x8*)(Bs + (wc + j * 16 + l15) * 32 + (quad << 3));
#pragma unroll
            for (int i = 0; i < 4; i++)
#pragma unroll
                for (int j = 0; j < 4; j++)
                    acc[i][j] = __builtin_amdgcn_mfma_f32_16x16x32_bf16(
                        af[i], bfr[j], acc[i][j], 0, 0, 0);
            __syncthreads();   // protect LDS from next tile's stores
        }
    }

    // ------------------ epilogue (C/D: row=quad*4+reg, col=lane&15) --------
    const int eg = (e_gate >= 0) ? e_gate : z;

    if constexpr (MODE == 0 || MODE == 1) {
        bf16* C = (bf16*)Cout + (long)z * out_z;
        const bf16* bb = bias + (long)z * bias_z;
        float gv[4][4];
        if constexpr (MODE == 1) {
#pragma unroll
            for (int i = 0; i < 4; i++)
#pragma unroll
                for (int rg = 0; rg < 4; rg++)
                    gv[i][rg] = gates[(row0 + m0 + wr + i * 16 + quad * 4 + rg) * 8 + eg];
        }
#pragma unroll
        for (int j = 0; j < 4; j++) {
            const int c = (int)n0 + wc + j * 16 + l15;
            const float bv = __bfloat162float(bb[c]);
#pragma unroll
            for (int i = 0; i < 4; i++) {
#pragma unroll
                for (int rg = 0; rg < 4; rg++) {
                    const long r = m0 + wr + i * 16 + quad * 4 + rg;
                    float v = fmaxf(acc[i][j][rg] + bv, 0.f);
                    if constexpr (MODE == 1) v *= gv[i][rg];
                    C[r * ldo + c] = __float2bfloat16(v);
                }
            }
        }
    } else if constexpr (MODE == 2) {
        float* C = (float*)Cout;
#pragma unroll
        for (int i = 0; i < 4; i++) {
#pragma unroll
            for (int rg = 0; rg < 4; rg++) {
                const long r = m0 + wr + i * 16 + quad * 4 + rg;
                const float g = gates[(row0 + r) * 8 + eg];
#pragma unroll
                for (int j = 0; j < 4; j++) {
                    const int c = (int)n0 + wc + j * 16 + l15;
                    const float b3 = __bfloat162float(eb3[eg * O_ + c]);
                    C[r * ldo + c] += acc[i][j][rg] + g * b3;
                }
            }
        }
    } else {  // MODE == 5: split-K, plain store into parts[z] (stride out_z)
        float* C = (float*)Cout + (long)z * out_z;
        const int e0 = z * 2;
        float b30[4], b31[4];
#pragma unroll
        for (int j = 0; j < 4; j++) {
            const int c = (int)n0 + wc + j * 16 + l15;
            b30[j] = __bfloat162float(eb3[e0 * O_ + c]);
            b31[j] = __bfloat162float(eb3[(e0 + 1) * O_ + c]);
        }
#pragma unroll
        for (int i = 0; i < 4; i++) {
#pragma unroll
            for (int rg = 0; rg < 4; rg++) {
                const long r = m0 + wr + i * 16 + quad * 4 + rg;
                const float g0 = gates[(row0 + r) * 8 + e0];
                const float g1 = gates[(row0 + r) * 8 + e0 + 1];
#pragma unroll
                for (int j = 0; j < 4; j++) {
                    const int c = (int)n0 + wc + j * 16 + l15;
                    C[(row0 + r) * ldo + c] =
                        acc[i][j][rg] + g0 * b30[j] + g1 * b31[j];
                }
            }
        }
    }
}

// ---------------------------------------------------------------------------
__global__ void zero_f32_k(float* __restrict__ p) {
    p[(long)blockIdx.x * 256 + threadIdx.x] = 0.f;
}
__global__ void out_cvt_k(const float* __restrict__ in, void* __restrict__ out,
                          const int* __restrict__ flag) {
    const long i = (long)blockIdx.x * 256 + threadIdx.x;
    if (*flag) ((float*)out)[i] = in[i];
    else       ((bf16*)out)[i] = __float2bfloat16(in[i]);
}
// sum 4 split-K partial buffers [4][B][O] -> d_out (fp32 or bf16 per flag)
__global__ void reduce4_k(const float* __restrict__ p, void* __restrict__ out,
                          const int* __restrict__ flag) {
    const long n = (long)B_ * O_;
    const long i = ((long)blockIdx.x * 256 + threadIdx.x) * 4;
    float4 a = *(const float4*)(p + i);
    float4 b = *(const float4*)(p + n + i);
    float4 c = *(const float4*)(p + 2 * n + i);
    float4 d = *(const float4*)(p + 3 * n + i);
    float4 s = {a.x + b.x + c.x + d.x, a.y + b.y + c.y + d.y,
                a.z + b.z + c.z + d.z, a.w + b.w + c.w + d.w};
    if (*flag) {
        *(float4*)((float*)out + i) = s;
    } else {
        bf16* o = (bf16*)out + i;
        o[0] = __float2bfloat16(s.x); o[1] = __float2bfloat16(s.y);
        o[2] = __float2bfloat16(s.z); o[3] = __float2bfloat16(s.w);
    }
}

// ---------------------------------------------------------------------------
extern "C" void kernel_launch(void* const* d_in, const int* in_sizes, int n_in,
                              void* d_out, int out_size, void* d_ws, size_t ws_size,
                              hipStream_t stream) {
    (void)in_sizes; (void)n_in; (void)out_size;
    const void* x   = d_in[0];
    const void* gw1 = d_in[1];
    const void* gb1 = d_in[2];
    const void* gw2 = d_in[3];
    const void* gb2 = d_in[4];
    const void* gw3 = d_in[5];
    const void* gb3 = d_in[6];
    const void* ew1 = d_in[7];
    const void* eb1 = d_in[8];
    const void* ew2 = d_in[9];
    const void* eb2 = d_in[10];
    const void* ew3 = d_in[11];
    const void* eb3 = d_in[12];

    char* ws = (char*)d_ws;
    size_t off = 0;
    auto alloc = [&](size_t n) { char* p = ws + off; off += (n + 255) & ~(size_t)255; return p; };

    int*  flag  = (int*)alloc(256);
    bf16* xc    = (bf16*)alloc((size_t)B_ * D_ * 2);
    bf16* gw1t  = (bf16*)alloc((size_t)256 * 1024 * 2);
    bf16* gw2t  = (bf16*)alloc((size_t)128 * 256 * 2);
    bf16* ew1t  = (bf16*)alloc((size_t)E_ * H_ * D_ * 2);
    bf16* ew2t  = (bf16*)alloc((size_t)E_ * H_ * H_ * 2);
    bf16* ew3t  = (bf16*)alloc((size_t)E_ * O_ * H_ * 2);
    bf16* gb1c  = (bf16*)alloc(256 * 2);
    bf16* gb2c  = (bf16*)alloc(128 * 2);
    bf16* gw3c  = (bf16*)alloc(1024 * 2);
    bf16* gb3c  = (bf16*)alloc(8 * 2);
    bf16* eb1c  = (bf16*)alloc((size_t)E_ * H_ * 2);
    bf16* eb2c  = (bf16*)alloc((size_t)E_ * H_ * 2);
    bf16* eb3c  = (bf16*)alloc((size_t)E_ * O_ * 2);
    bf16* g1    = (bf16*)alloc((size_t)B_ * 256 * 2);
    bf16* g2b   = (bf16*)alloc((size_t)B_ * 128 * 2);
    float* gates = (float*)alloc((size_t)B_ * 8 * 4);

    const size_t small = off;
    // path A: h1c + h2c ([E][BC][H] bf16 each) + parts fp32 [4][B][O]
    const size_t needA = small + 2ull * ((size_t)E_ * BC_ * H_ * 2 + 256)
                               + (4ull * B_ * O_ * 4 + 256) + 4096;
    const bool pathA = ws_size >= needA;

    // 1) detect input dtype (flag=1 -> fp32)
    detect_k<<<1, 256, 0, stream>>>((const unsigned short*)x, flag);

    // 2) canonicalize to bf16
    cvt_k<<<4096, 256, 0, stream>>>(x, xc, flag, (long)B_ * D_);
    cvt_k<<<1, 256, 0, stream>>>(gb1, gb1c, flag, 256);
    cvt_k<<<1, 256, 0, stream>>>(gb2, gb2c, flag, 128);
    cvt_k<<<4, 256, 0, stream>>>(gw3, gw3c, flag, 1024);
    cvt_k<<<1, 256, 0, stream>>>(gb3, gb3c, flag, 8);
    cvt_k<<<16, 256, 0, stream>>>(eb1, eb1c, flag, (long)E_ * H_);
    cvt_k<<<16, 256, 0, stream>>>(eb2, eb2c, flag, (long)E_ * H_);
    cvt_k<<<8, 256, 0, stream>>>(eb3, eb3c, flag, (long)E_ * O_);

    // 3) weight transposes (K-contiguous rows, canonical bf16)
    transpose_k<<<dim3(256 / 32, 1024 / 32, 1), dim3(32, 8), 0, stream>>>(gw1, gw1t, flag, 1024, 256);
    transpose_k<<<dim3(128 / 32, 256 / 32, 1), dim3(32, 8), 0, stream>>>(gw2, gw2t, flag, 256, 128);
    transpose_k<<<dim3(H_ / 32, D_ / 32, E_), dim3(32, 8), 0, stream>>>(ew1, ew1t, flag, D_, H_);
    transpose_k<<<dim3(H_ / 32, H_ / 32, E_), dim3(32, 8), 0, stream>>>(ew2, ew2t, flag, H_, H_);
    transpose_k<<<dim3(O_ / 32, H_ / 32, E_), dim3(32, 8), 0, stream>>>(ew3, ew3t, flag, H_, O_);

    // 4) gating network
    gemm_bt<0><<<dim3(2, 128, 1), 256, 0, stream>>>(
        xc, gw1t, gb1c, nullptr, g1, nullptr, nullptr,
        1024, 1024, 256, 1024, 0, 0, 0, 0, 0, 0, 0, 0, 0);
    gemm_bt<0><<<dim3(1, 128, 1), 256, 0, stream>>>(
        g1, gw2t, gb2c, nullptr, g2b, nullptr, nullptr,
        256, 256, 128, 256, 0, 0, 0, 0, 0, 0, 0, 0, 0);
    gate3_softmax_k<<<dim3(B_ / 256), 256, 0, stream>>>(g2b, gw3c, gb3c, gates);

    // 5) experts
    if (pathA) {
        bf16* h1c = (bf16*)alloc((size_t)E_ * BC_ * H_ * 2);
        bf16* h2c = (bf16*)alloc((size_t)E_ * BC_ * H_ * 2);
        float* parts = (float*)alloc(4ull * B_ * O_ * 4);
        for (int ci = 0; ci < B_ / BC_; ci++) {
            const long rb = (long)ci * BC_;
            // L1 (batched z=e): h1c[e][0..BC)[H] = relu(x_chunk @ ew1[e] + eb1[e])
            gemm_bt<0><<<dim3(4, BC_ / 128, 8), 256, 0, stream>>>(
                xc + rb * D_, ew1t, eb1c, nullptr, h1c, nullptr, nullptr,
                D_, D_, H_, D_,
                0, (long)H_ * D_, H_, (long)BC_ * H_, 0, 0, 0, 0, 0);
            // L2 (batched, gate folded): h2c[e][0..BC)[H]
            gemm_bt<1><<<dim3(4, BC_ / 128, 8), 256, 0, stream>>>(
                h1c, ew2t, eb2c, gates, h2c, nullptr, nullptr,
                H_, H_, H_, H_,
                (long)BC_ * H_, (long)H_ * H_, H_, (long)BC_ * H_, -1, 0, 0, 0, rb);
            // L3 split-K (no atomics): z=4 splits x 2 experts (K=1024 each)
            gemm_bt<5><<<dim3(2, BC_ / 128, 4), 256, 0, stream>>>(
                h2c, ew3t, nullptr, gates, parts, eb3c, nullptr,
                H_, H_, O_, 1024,
                2L * BC_ * H_, 2L * O_ * H_, 0, (long)B_ * O_,
                2 /*epz*/, 512, (long)BC_ * H_, (long)O_ * H_, rb);
        }
        reduce4_k<<<dim3(B_ * O_ / 1024), 256, 0, stream>>>(parts, d_out, flag);
    } else {
        bf16* h1s = (bf16*)alloc((size_t)B_ * H_ * 2);
        bf16* h2s = (bf16*)alloc((size_t)B_ * H_ * 2);
        float* oacc = (float*)alloc((size_t)B_ * O_ * 4);
        zero_f32_k<<<dim3(B_ * O_ / 256), 256, 0, stream>>>(oacc);
        for (int e = 0; e < E_; e++) {
            gemm_bt<0><<<dim3(4, 128, 1), 256, 0, stream>>>(
                xc, ew1t + (size_t)e * H_ * D_, eb1c + (size_t)e * H_, nullptr, h1s, nullptr, nullptr,
                1024, 1024, 512, 1024, 0, 0, 0, 0, 0, 0, 0, 0, 0);
            gemm_bt<1><<<dim3(4, 128, 1), 256, 0, stream>>>(
                h1s, ew2t + (size_t)e * H_ * H_, eb2c + (size_t)e * H_, gates, h2s, nullptr, nullptr,
                512, 512, 512, 512, 0, 0, 0, 0, e, 0, 0, 0, 0);
            gemm_bt<2><<<dim3(2, 128, 1), 256, 0, stream>>>(
                h2s, ew3t + (size_t)e * O_ * H_, nullptr, gates, oacc, eb3c, nullptr,
                512, 512, 256, 512, 0, 0, 0, 0, e, 0, 0, 0, 0);
        }
        out_cvt_k<<<dim3(B_ * O_ / 256), 256, 0, stream>>>(oacc, d_out, flag);
    }
}